// Round 2
// baseline (3680.063 us; speedup 1.0000x reference)
//
#include <hip/hip_runtime.h>
#include <hip/hip_bf16.h>

// GCN: 3x GCNConv(sigmoid edge weights, sym-norm, self-loops) + ReLU,
// then 2M-edge gather-concat -> fused linear(64->3).
//
// Key algebraic simplifications vs reference:
//  - deg/dinv/norm computed ONCE (identical across the 3 conv layers)
//  - head: (concat@Wl1+bl1)@Wl2+bl2 == concat@(Wl1@Wl2) + (bl1@Wl2+bl2)
//    (no activation between the linears), fused on device.

__device__ __forceinline__ float sigmoidf_(float x) {
    return 1.0f / (1.0f + __expf(-x));
}

// ---- degree accumulation: deg[dst] += sigmoid(ew[e]) (self-loop "+1" added later)
__global__ void deg_kernel(const int* __restrict__ dst, const float* __restrict__ ew,
                           float* __restrict__ deg, int ne) {
    int e = blockIdx.x * blockDim.x + threadIdx.x;
    if (e >= ne) return;
    unsafeAtomicAdd(&deg[dst[e]], sigmoidf_(ew[e]));
}

// ---- dinv[i] = rsqrt(deg[i] + 1)  (in-place; self-loop weight 1 folded in; deg+1 >= 1 > 0)
__global__ void dinv_kernel(float* __restrict__ deg, int n) {
    int i = blockIdx.x * blockDim.x + threadIdx.x;
    if (i >= n) return;
    deg[i] = rsqrtf(deg[i] + 1.0f);
}

// ---- norm[e] = dinv[src] * sigmoid(ew) * dinv[dst]
__global__ void norm_kernel(const int* __restrict__ src, const int* __restrict__ dst,
                            const float* __restrict__ ew, const float* __restrict__ dinv,
                            float* __restrict__ norm, int ne) {
    int e = blockIdx.x * blockDim.x + threadIdx.x;
    if (e >= ne) return;
    norm[e] = dinv[src[e]] * sigmoidf_(ew[e]) * dinv[dst[e]];
}

// ---- per-node dense: xw = (relu?)x @ W ; agg_init = b + xw * dinv^2 (self-loop msg)
template <int IN, int OUT, bool RELU_IN>
__global__ void xw_kernel(const float* __restrict__ xin, const float* __restrict__ W,
                          const float* __restrict__ b, const float* __restrict__ dinv,
                          float* __restrict__ xw, float* __restrict__ agg, int n) {
    __shared__ float Ws[IN * OUT];
    __shared__ float bs[OUT];
    for (int i = threadIdx.x; i < IN * OUT; i += blockDim.x) Ws[i] = W[i];
    if (threadIdx.x < OUT) bs[threadIdx.x] = b[threadIdx.x];
    __syncthreads();
    int i = blockIdx.x * blockDim.x + threadIdx.x;
    if (i >= n) return;
    float xi[IN];
#pragma unroll
    for (int k = 0; k < IN; ++k) {
        float v = xin[(long)i * IN + k];
        if (RELU_IN) v = fmaxf(v, 0.0f);
        xi[k] = v;
    }
    float d = dinv[i];
    float d2 = d * d;
#pragma unroll
    for (int o = 0; o < OUT; ++o) {
        float acc = 0.0f;
#pragma unroll
        for (int k = 0; k < IN; ++k) acc = fmaf(xi[k], Ws[k * OUT + o], acc);
        xw[(long)i * OUT + o] = acc;
        agg[(long)i * OUT + o] = bs[o] + acc * d2;
    }
}

// ---- edge scatter: agg[dst] += xw[src] * norm[e]; F/4 lanes per edge, float4 per lane
template <int F>
__global__ void scatter_kernel(const int* __restrict__ src, const int* __restrict__ dst,
                               const float* __restrict__ norm, const float* __restrict__ xw,
                               float* __restrict__ agg, int ne) {
    constexpr int CPE = F / 4;  // float4 chunks per edge
    long long t = (long long)blockIdx.x * blockDim.x + threadIdx.x;
    long long e = t / CPE;
    int c = (int)(t % CPE);
    if (e >= ne) return;
    int s = src[e], d = dst[e];
    float nrm = norm[e];
    const float4 v = *reinterpret_cast<const float4*>(xw + (long)s * F + c * 4);
    float* ap = agg + (long)d * F + c * 4;
    unsafeAtomicAdd(ap + 0, v.x * nrm);
    unsafeAtomicAdd(ap + 1, v.y * nrm);
    unsafeAtomicAdd(ap + 2, v.z * nrm);
    unsafeAtomicAdd(ap + 3, v.w * nrm);
}

// ---- fuse head weights: wf[64*3] = Wl1[64,4] @ Wl2[4,3]; bf[3] = bl1 @ Wl2 + bl2
__global__ void fuse_kernel(const float* __restrict__ Wl1, const float* __restrict__ bl1,
                            const float* __restrict__ Wl2, const float* __restrict__ bl2,
                            float* __restrict__ wf, float* __restrict__ bf) {
    int t = threadIdx.x;
    if (t < 64 * 3) {
        int f = t / 3, j = t % 3;
        float acc = 0.0f;
#pragma unroll
        for (int k = 0; k < 4; ++k) acc = fmaf(Wl1[f * 4 + k], Wl2[k * 3 + j], acc);
        wf[t] = acc;
    }
    if (t < 3) {
        float acc = bl2[t];
#pragma unroll
        for (int k = 0; k < 4; ++k) acc = fmaf(bl1[k], Wl2[k * 3 + t], acc);
        bf[t] = acc;
    }
}

// ---- head: out[e] = [relu(h[a]), relu(h[b])] @ wf + bf   (h rows are 32 floats)
__global__ void mlp_kernel(const int* __restrict__ w2b, const float* __restrict__ h,
                           const float* __restrict__ wf, const float* __restrict__ bf,
                           float* __restrict__ out, int ne, int off) {
    __shared__ float Ws[192];
    __shared__ float bs[3];
    for (int i = threadIdx.x; i < 192; i += blockDim.x) Ws[i] = wf[i];
    if (threadIdx.x < 3) bs[threadIdx.x] = bf[threadIdx.x];
    __syncthreads();
    int e = blockIdx.x * blockDim.x + threadIdx.x;
    if (e >= ne) return;
    int na = w2b[e];
    int nb = w2b[(long)off + e];
    float a0 = bs[0], a1 = bs[1], a2 = bs[2];
    const float4* ra = reinterpret_cast<const float4*>(h + (long)na * 32);
    const float4* rb = reinterpret_cast<const float4*>(h + (long)nb * 32);
#pragma unroll
    for (int c = 0; c < 8; ++c) {
        float4 v = ra[c];
        float vv[4] = {v.x, v.y, v.z, v.w};
#pragma unroll
        for (int j = 0; j < 4; ++j) {
            float u = fmaxf(vv[j], 0.0f);
            int f = c * 4 + j;
            a0 = fmaf(u, Ws[f * 3 + 0], a0);
            a1 = fmaf(u, Ws[f * 3 + 1], a1);
            a2 = fmaf(u, Ws[f * 3 + 2], a2);
        }
    }
#pragma unroll
    for (int c = 0; c < 8; ++c) {
        float4 v = rb[c];
        float vv[4] = {v.x, v.y, v.z, v.w};
#pragma unroll
        for (int j = 0; j < 4; ++j) {
            float u = fmaxf(vv[j], 0.0f);
            int f = 32 + c * 4 + j;
            a0 = fmaf(u, Ws[f * 3 + 0], a0);
            a1 = fmaf(u, Ws[f * 3 + 1], a1);
            a2 = fmaf(u, Ws[f * 3 + 2], a2);
        }
    }
    out[(long)e * 3 + 0] = a0;
    out[(long)e * 3 + 1] = a1;
    out[(long)e * 3 + 2] = a2;
}

extern "C" void kernel_launch(void* const* d_in, const int* in_sizes, int n_in,
                              void* d_out, int out_size, void* d_ws, size_t ws_size,
                              hipStream_t stream) {
    const float* x   = (const float*)d_in[0];
    const int* eidx  = (const int*)d_in[1];
    const int* w2b   = (const int*)d_in[2];
    const float* ew  = (const float*)d_in[3];
    const float* W1  = (const float*)d_in[4];
    const float* b1  = (const float*)d_in[5];
    const float* W2  = (const float*)d_in[6];
    const float* b2  = (const float*)d_in[7];
    const float* W3  = (const float*)d_in[8];
    const float* b3  = (const float*)d_in[9];
    const float* Wl1 = (const float*)d_in[10];
    const float* bl1 = (const float*)d_in[11];
    const float* Wl2 = (const float*)d_in[12];
    const float* bl2 = (const float*)d_in[13];
    float* out = (float*)d_out;

    const int n  = in_sizes[0] / 7;       // 200000
    const int ne = in_sizes[1] / 2;       // 4000000
    const int nw = in_sizes[2] / 2;       // 2000000
    const int* src = eidx;
    const int* dst = eidx + ne;

    // workspace layout (floats)
    float* ws    = (float*)d_ws;
    float* deg   = ws;                      // n           (becomes dinv in-place)
    float* norm  = deg + n;                 // ne
    float* wf    = norm + ne;               // 192
    float* bf    = wf + 192;                // 3 (+pad)
    float* xwbuf = wf + 256;                // n*32 max
    float* aggA  = xwbuf + (long)n * 32;    // n*32 max
    float* aggB  = aggA + (long)n * 32;     // n*16 max

    const int B = 256;
    auto blks = [&](long long t) { return (int)((t + B - 1) / B); };

    // 1. deg = sum_dst sigmoid(ew);  dinv = rsqrt(deg+1)
    (void)hipMemsetAsync(deg, 0, (size_t)n * sizeof(float), stream);
    deg_kernel<<<blks(ne), B, 0, stream>>>(dst, ew, deg, ne);
    dinv_kernel<<<blks(n), B, 0, stream>>>(deg, n);
    norm_kernel<<<blks(ne), B, 0, stream>>>(src, dst, ew, deg, norm, ne);

    // 2. layer 1: 7 -> 8
    xw_kernel<7, 8, false><<<blks(n), B, 0, stream>>>(x, W1, b1, deg, xwbuf, aggA, n);
    scatter_kernel<8><<<blks((long long)ne * 2), B, 0, stream>>>(src, dst, norm, xwbuf, aggA, ne);

    // 3. layer 2: 8 -> 16 (relu on input)
    xw_kernel<8, 16, true><<<blks(n), B, 0, stream>>>(aggA, W2, b2, deg, xwbuf, aggB, n);
    scatter_kernel<16><<<blks((long long)ne * 4), B, 0, stream>>>(src, dst, norm, xwbuf, aggB, ne);

    // 4. layer 3: 16 -> 32 (relu on input)
    xw_kernel<16, 32, true><<<blks(n), B, 0, stream>>>(aggB, W3, b3, deg, xwbuf, aggA, n);
    scatter_kernel<32><<<blks((long long)ne * 8), B, 0, stream>>>(src, dst, norm, xwbuf, aggA, ne);

    // 5. head (relu folded into gather; Wl1@Wl2 fused)
    fuse_kernel<<<1, 192, 0, stream>>>(Wl1, bl1, Wl2, bl2, wf, bf);
    mlp_kernel<<<blks(nw), B, 0, stream>>>(w2b, aggA, wf, bf, out, nw, nw);
}

// Round 3
// 1048.564 us; speedup vs baseline: 3.5096x; 3.5096x over previous
//
#include <hip/hip_runtime.h>
#include <hip/hip_bf16.h>

// GCN 3-layer + edge-MLP head, CSR-gather formulation (no atomics in hot loops).
//
// Algebra:
//  - deg/dinv/norm computed once (shared by all 3 convs).
//  - conv: out = (sum_{e->i} norm_e * h[src_e] + dinv_i^2 * h[i]) @ W + b
//    -> aggregate in the NARROW input space, dense transform once per node.
//  - head: out[e] = concat(h3[a],h3[b]) @ (Wl1@Wl2) + (bl1@Wl2+bl2)
//        = p[a] + q[b],  p = h3@wf[0:32] + bf, q = h3@wf[32:64]
//    p,q fused into layer-3 dense epilogue; h3 never materialized.

__device__ __forceinline__ float sigmoidf_(float x) {
    return 1.0f / (1.0f + __expf(-x));
}

// ---- per-edge histogram (int) + weighted degree (float), both L2-resident tables
__global__ void count_deg_kernel(const int* __restrict__ dst, const float* __restrict__ ew,
                                 int* __restrict__ cnt, float* __restrict__ deg, int ne) {
    int e = blockIdx.x * blockDim.x + threadIdx.x;
    if (e >= ne) return;
    int d = dst[e];
    atomicAdd(&cnt[d], 1);
    unsafeAtomicAdd(&deg[d], sigmoidf_(ew[e]));
}

__global__ void dinv_kernel(float* __restrict__ deg, int n) {
    int i = blockIdx.x * blockDim.x + threadIdx.x;
    if (i >= n) return;
    deg[i] = rsqrtf(deg[i] + 1.0f);  // self-loop weight 1 folded in
}

// ---- exclusive scan of cnt -> C (3 kernels), block size 256
__global__ void scan1_kernel(const int* __restrict__ cnt, int* __restrict__ C,
                             int* __restrict__ bsum, int n) {
    __shared__ int tmp[256];
    int gid = blockIdx.x * 256 + threadIdx.x;
    int v = (gid < n) ? cnt[gid] : 0;
    tmp[threadIdx.x] = v;
    __syncthreads();
    for (int off = 1; off < 256; off <<= 1) {
        int t = (threadIdx.x >= off) ? tmp[threadIdx.x - off] : 0;
        __syncthreads();
        tmp[threadIdx.x] += t;
        __syncthreads();
    }
    if (gid < n) C[gid] = tmp[threadIdx.x] - v;  // exclusive
    if (threadIdx.x == 255) bsum[blockIdx.x] = tmp[255];
}

__global__ void scan2_kernel(int* __restrict__ bsum, int nb) {
    __shared__ int tmp[1024];
    int tid = threadIdx.x;
    int v = (tid < nb) ? bsum[tid] : 0;
    tmp[tid] = v;
    __syncthreads();
    for (int off = 1; off < 1024; off <<= 1) {
        int t = (tid >= off) ? tmp[tid - off] : 0;
        __syncthreads();
        tmp[tid] += t;
        __syncthreads();
    }
    if (tid < nb) bsum[tid] = tmp[tid] - v;  // exclusive
}

__global__ void scan3_kernel(int* __restrict__ C, const int* __restrict__ bsum, int n) {
    int gid = blockIdx.x * 256 + threadIdx.x;
    if (gid < n) C[gid] += bsum[blockIdx.x];
}

// ---- CSR fill: edata[pos] = (src, norm) sorted by dst; C becomes row-END array
__global__ void fill_kernel(const int* __restrict__ src, const int* __restrict__ dst,
                            const float* __restrict__ ew, const float* __restrict__ dinv,
                            int* __restrict__ C, float2* __restrict__ edata, int ne) {
    int e = blockIdx.x * blockDim.x + threadIdx.x;
    if (e >= ne) return;
    int s = src[e], d = dst[e];
    float w = dinv[s] * sigmoidf_(ew[e]) * dinv[d];
    int pos = atomicAdd(&C[d], 1);
    float2 v;
    v.x = __int_as_float(s);
    v.y = w;
    edata[pos] = v;
}

// ---- layer-1 pre-transform: xw1 = x @ W1 (7 -> 8, no bias yet)
__global__ void xw1_kernel(const float* __restrict__ x, const float* __restrict__ W,
                           float* __restrict__ xw, int n) {
    __shared__ float Ws[56];
    if (threadIdx.x < 56) Ws[threadIdx.x] = W[threadIdx.x];
    __syncthreads();
    int i = blockIdx.x * blockDim.x + threadIdx.x;
    if (i >= n) return;
    float xi[7];
#pragma unroll
    for (int k = 0; k < 7; ++k) xi[k] = x[(size_t)i * 7 + k];
#pragma unroll
    for (int o = 0; o < 8; ++o) {
        float acc = 0.0f;
#pragma unroll
        for (int k = 0; k < 7; ++k) acc = fmaf(xi[k], Ws[k * 8 + o], acc);
        xw[(size_t)i * 8 + o] = acc;
    }
}

// ---- gather-reduce: out[i] = sum_e norm*feat[src] + d2*feat[i]  (F/4 lanes per node)
// BR: epilogue out = relu(acc + bias) (used when feat is already in output space)
template <int F, bool BR>
__global__ void gather_kernel(const float* __restrict__ feat, const float* __restrict__ dinv,
                              const int* __restrict__ Cend, const float2* __restrict__ edata,
                              const float* __restrict__ bias, float* __restrict__ out, int n) {
    constexpr int L = F / 4;
    long long t = (long long)blockIdx.x * blockDim.x + threadIdx.x;
    int i = (int)(t / L);
    int c = (int)(t % L);
    if (i >= n) return;
    int beg = (i == 0) ? 0 : Cend[i - 1];
    int end = Cend[i];
    float dv = dinv[i];
    float d2 = dv * dv;
    float4 acc = *reinterpret_cast<const float4*>(feat + (size_t)i * F + c * 4);
    acc.x *= d2; acc.y *= d2; acc.z *= d2; acc.w *= d2;
    for (int k = beg; k < end; ++k) {
        float2 ed = edata[k];
        int s = __float_as_int(ed.x);
        float w = ed.y;
        float4 v = *reinterpret_cast<const float4*>(feat + (size_t)s * F + c * 4);
        acc.x = fmaf(v.x, w, acc.x);
        acc.y = fmaf(v.y, w, acc.y);
        acc.z = fmaf(v.z, w, acc.z);
        acc.w = fmaf(v.w, w, acc.w);
    }
    if (BR) {
        acc.x = fmaxf(acc.x + bias[c * 4 + 0], 0.0f);
        acc.y = fmaxf(acc.y + bias[c * 4 + 1], 0.0f);
        acc.z = fmaxf(acc.z + bias[c * 4 + 2], 0.0f);
        acc.w = fmaxf(acc.w + bias[c * 4 + 3], 0.0f);
    }
    *reinterpret_cast<float4*>(out + (size_t)i * F + c * 4) = acc;
}

// ---- dense + relu: out = relu(raw @ W + b), IN % 4 == 0
template <int IN, int OUT>
__global__ void dense_kernel(const float* __restrict__ raw, const float* __restrict__ W,
                             const float* __restrict__ b, float* __restrict__ out, int n) {
    __shared__ float Ws[IN * OUT];
    __shared__ float bs[OUT];
    for (int k = threadIdx.x; k < IN * OUT; k += blockDim.x) Ws[k] = W[k];
    if (threadIdx.x < OUT) bs[threadIdx.x] = b[threadIdx.x];
    __syncthreads();
    int i = blockIdx.x * blockDim.x + threadIdx.x;
    if (i >= n) return;
    float xi[IN];
#pragma unroll
    for (int c = 0; c < IN / 4; ++c) {
        float4 v = *reinterpret_cast<const float4*>(raw + (size_t)i * IN + c * 4);
        xi[c * 4 + 0] = v.x; xi[c * 4 + 1] = v.y; xi[c * 4 + 2] = v.z; xi[c * 4 + 3] = v.w;
    }
#pragma unroll
    for (int o = 0; o < OUT; ++o) {
        float acc = bs[o];
#pragma unroll
        for (int k = 0; k < IN; ++k) acc = fmaf(xi[k], Ws[k * OUT + o], acc);
        out[(size_t)i * OUT + o] = fmaxf(acc, 0.0f);
    }
}

// ---- fuse head weights: wf[64*3] = Wl1[64,4] @ Wl2[4,3]; bf[3] = bl1 @ Wl2 + bl2
__global__ void fuse_kernel(const float* __restrict__ Wl1, const float* __restrict__ bl1,
                            const float* __restrict__ Wl2, const float* __restrict__ bl2,
                            float* __restrict__ wf, float* __restrict__ bf) {
    int t = threadIdx.x;
    if (t < 64 * 3) {
        int f = t / 3, j = t % 3;
        float acc = 0.0f;
#pragma unroll
        for (int k = 0; k < 4; ++k) acc = fmaf(Wl1[f * 4 + k], Wl2[k * 3 + j], acc);
        wf[t] = acc;
    }
    if (t < 3) {
        float acc = bl2[t];
#pragma unroll
        for (int k = 0; k < 4; ++k) acc = fmaf(bl1[k], Wl2[k * 3 + t], acc);
        bf[t] = acc;
    }
}

// ---- layer-3 dense fused with head projection:
// h = relu(raw16 @ W3 + b3);  p = h@wf[0:32] + bf;  q = h@wf[32:64]
// pq[i*8 + 0..2] = p, pq[i*8 + 4..6] = q  (h3 never materialized)
__global__ void dense3_kernel(const float* __restrict__ raw, const float* __restrict__ W,
                              const float* __restrict__ b, const float* __restrict__ wf,
                              const float* __restrict__ bf, float* __restrict__ pq, int n) {
    __shared__ float Ws[512];
    __shared__ float bs[32];
    __shared__ float wfs[192];
    __shared__ float bfs[3];
    for (int k = threadIdx.x; k < 512; k += blockDim.x) Ws[k] = W[k];
    if (threadIdx.x < 32) bs[threadIdx.x] = b[threadIdx.x];
    for (int k = threadIdx.x; k < 192; k += blockDim.x) wfs[k] = wf[k];
    if (threadIdx.x < 3) bfs[threadIdx.x] = bf[threadIdx.x];
    __syncthreads();
    int i = blockIdx.x * blockDim.x + threadIdx.x;
    if (i >= n) return;
    float xi[16];
#pragma unroll
    for (int c = 0; c < 4; ++c) {
        float4 v = *reinterpret_cast<const float4*>(raw + (size_t)i * 16 + c * 4);
        xi[c * 4 + 0] = v.x; xi[c * 4 + 1] = v.y; xi[c * 4 + 2] = v.z; xi[c * 4 + 3] = v.w;
    }
    float p0 = bfs[0], p1 = bfs[1], p2 = bfs[2];
    float q0 = 0.0f, q1 = 0.0f, q2 = 0.0f;
#pragma unroll
    for (int o = 0; o < 32; ++o) {
        float h = bs[o];
#pragma unroll
        for (int k = 0; k < 16; ++k) h = fmaf(xi[k], Ws[k * 32 + o], h);
        h = fmaxf(h, 0.0f);
        p0 = fmaf(h, wfs[o * 3 + 0], p0);
        p1 = fmaf(h, wfs[o * 3 + 1], p1);
        p2 = fmaf(h, wfs[o * 3 + 2], p2);
        q0 = fmaf(h, wfs[(32 + o) * 3 + 0], q0);
        q1 = fmaf(h, wfs[(32 + o) * 3 + 1], q1);
        q2 = fmaf(h, wfs[(32 + o) * 3 + 2], q2);
    }
    float4 P = {p0, p1, p2, 0.0f};
    float4 Q = {q0, q1, q2, 0.0f};
    *reinterpret_cast<float4*>(pq + (size_t)i * 8 + 0) = P;
    *reinterpret_cast<float4*>(pq + (size_t)i * 8 + 4) = Q;
}

// ---- head: out[e] = p[a] + q[b]   (bf already folded into p)
__global__ void head_kernel(const int* __restrict__ w2b, const float4* __restrict__ pq,
                            float* __restrict__ out, int nw) {
    int e = blockIdx.x * blockDim.x + threadIdx.x;
    if (e >= nw) return;
    int a = w2b[e];
    int b = w2b[(size_t)nw + e];
    float4 P = pq[(size_t)a * 2 + 0];
    float4 Q = pq[(size_t)b * 2 + 1];
    out[(size_t)e * 3 + 0] = P.x + Q.x;
    out[(size_t)e * 3 + 1] = P.y + Q.y;
    out[(size_t)e * 3 + 2] = P.z + Q.z;
}

extern "C" void kernel_launch(void* const* d_in, const int* in_sizes, int n_in,
                              void* d_out, int out_size, void* d_ws, size_t ws_size,
                              hipStream_t stream) {
    const float* x   = (const float*)d_in[0];
    const int* eidx  = (const int*)d_in[1];
    const int* w2b   = (const int*)d_in[2];
    const float* ew  = (const float*)d_in[3];
    const float* W1  = (const float*)d_in[4];
    const float* b1  = (const float*)d_in[5];
    const float* W2  = (const float*)d_in[6];
    const float* b2  = (const float*)d_in[7];
    const float* W3  = (const float*)d_in[8];
    const float* b3  = (const float*)d_in[9];
    const float* Wl1 = (const float*)d_in[10];
    const float* bl1 = (const float*)d_in[11];
    const float* Wl2 = (const float*)d_in[12];
    const float* bl2 = (const float*)d_in[13];
    float* out = (float*)d_out;

    const int n  = in_sizes[0] / 7;   // 200000
    const int ne = in_sizes[1] / 2;   // 4000000
    const int nw = in_sizes[2] / 2;   // 2000000
    const int* src = eidx;
    const int* dst = eidx + ne;

    // ---- workspace layout (floats) ----
    float* ws    = (float*)d_ws;
    float* deg   = ws;                         // n (becomes dinv in-place)
    int*   cnt   = (int*)(ws + n);             // n
    int*   C     = (int*)(ws + 2 * (size_t)n); // n (starts -> cursors -> ends)
    int*   bsum  = (int*)(ws + 3 * (size_t)n); // 1024
    float* wf    = ws + 3 * (size_t)n + 1024;  // 192
    float* bf    = wf + 192;                   // 16 (pad)
    float* edata = bf + 16;                    // 2*ne (float2 per edge), 8B-aligned
    float* xw1   = edata + 2 * (size_t)ne;     // n*8
    float* h1    = xw1 + (size_t)n * 8;        // n*8
    float* h2    = h1 + (size_t)n * 8;         // n*16
    float* raw   = h2 + (size_t)n * 16;        // n*16 (shared by L2/L3 gathers)
    float* pq    = raw + (size_t)n * 16;       // n*8
    // total ~ 59n + 2*ne + ~1.3K floats ~= 79 MB

    const int B = 256;
    auto blks = [&](long long t) { return (int)((t + B - 1) / B); };
    const int nb = blks(n);  // 782

    // 1. zero deg + cnt (adjacent), histogram + weighted degree
    (void)hipMemsetAsync(deg, 0, 2 * (size_t)n * sizeof(float), stream);
    count_deg_kernel<<<blks(ne), B, 0, stream>>>(dst, ew, cnt, deg, ne);
    dinv_kernel<<<nb, B, 0, stream>>>(deg, n);

    // 2. exclusive scan cnt -> C
    scan1_kernel<<<nb, B, 0, stream>>>(cnt, C, bsum, n);
    scan2_kernel<<<1, 1024, 0, stream>>>(bsum, nb);
    scan3_kernel<<<nb, B, 0, stream>>>(C, bsum, n);

    // 3. CSR fill (C -> row ends)
    fill_kernel<<<blks(ne), B, 0, stream>>>(src, dst, ew, deg, C, (float2*)edata, ne);

    // 4. layer 1: xw1 = x@W1; h1 = relu(gather(xw1) + b1)
    xw1_kernel<<<nb, B, 0, stream>>>(x, W1, xw1, n);
    gather_kernel<8, true><<<blks((long long)n * 2), B, 0, stream>>>(
        xw1, deg, C, (const float2*)edata, b1, h1, n);

    // 5. layer 2: raw8 = gather(h1); h2 = relu(raw8@W2 + b2)
    gather_kernel<8, false><<<blks((long long)n * 2), B, 0, stream>>>(
        h1, deg, C, (const float2*)edata, nullptr, raw, n);
    dense_kernel<8, 16><<<nb, B, 0, stream>>>(raw, W2, b2, h2, n);

    // 6. layer 3 + head projection: raw16 = gather(h2); pq = dense3(raw16)
    gather_kernel<16, false><<<blks((long long)n * 4), B, 0, stream>>>(
        h2, deg, C, (const float2*)edata, nullptr, raw, n);
    fuse_kernel<<<1, 192, 0, stream>>>(Wl1, bl1, Wl2, bl2, wf, bf);
    dense3_kernel<<<nb, B, 0, stream>>>(raw, W3, b3, wf, bf, pq, n);

    // 7. head: out[e] = p[a] + q[b]
    head_kernel<<<blks(nw), B, 0, stream>>>(w2b, (const float4*)pq, out, nw);
}

// Round 4
// 795.832 us; speedup vs baseline: 4.6242x; 1.3176x over previous
//
#include <hip/hip_runtime.h>
#include <hip/hip_bf16.h>

// GCN 3-layer + edge-MLP head, CSR-gather formulation.
// R4: atomic-minimized CSR build (4M int atomics total):
//  - edata stores (src, sig(ew)) only -> no dinv dependency, no float atomics.
//  - count pass records off[e] = atomicAdd(cnt[dst],1); fill uses C[dst]+off[e]
//    (no cursor atomics). deg computed sequentially from CSR rows.
//  - all dinv factors folded into dense/gather epilogues:
//      g = dinv (.) h ;  conv_raw_i = dinv_i * (sum_e sig_e * g_src + g_i)
//  - head: out[e] = p[a] + q[b], p/q fused into layer-3 dense epilogue.

__device__ __forceinline__ float sigmoidf_(float x) {
    return 1.0f / (1.0f + __expf(-x));
}

// ---- pass 1: histogram + per-edge bucket offset (the ONLY atomic pass)
__global__ void count_kernel(const int* __restrict__ dst, int* __restrict__ cnt,
                             int* __restrict__ off, int ne) {
    int e = blockIdx.x * blockDim.x + threadIdx.x;
    if (e >= ne) return;
    off[e] = atomicAdd(&cnt[dst[e]], 1);
}

// ---- exclusive scan of cnt -> C (3 kernels), block size 256; C[n] = ne
__global__ void scan1_kernel(const int* __restrict__ cnt, int* __restrict__ C,
                             int* __restrict__ bsum, int n) {
    __shared__ int tmp[256];
    int gid = blockIdx.x * 256 + threadIdx.x;
    int v = (gid < n) ? cnt[gid] : 0;
    tmp[threadIdx.x] = v;
    __syncthreads();
    for (int o = 1; o < 256; o <<= 1) {
        int t = (threadIdx.x >= o) ? tmp[threadIdx.x - o] : 0;
        __syncthreads();
        tmp[threadIdx.x] += t;
        __syncthreads();
    }
    if (gid < n) C[gid] = tmp[threadIdx.x] - v;  // exclusive
    if (threadIdx.x == 255) bsum[blockIdx.x] = tmp[255];
}

__global__ void scan2_kernel(int* __restrict__ bsum, int nb) {
    __shared__ int tmp[1024];
    int tid = threadIdx.x;
    int v = (tid < nb) ? bsum[tid] : 0;
    tmp[tid] = v;
    __syncthreads();
    for (int o = 1; o < 1024; o <<= 1) {
        int t = (tid >= o) ? tmp[tid - o] : 0;
        __syncthreads();
        tmp[tid] += t;
        __syncthreads();
    }
    if (tid < nb) bsum[tid] = tmp[tid] - v;  // exclusive
}

__global__ void scan3_kernel(int* __restrict__ C, const int* __restrict__ bsum,
                             int n, int ne) {
    int gid = blockIdx.x * 256 + threadIdx.x;
    if (gid < n) C[gid] += bsum[blockIdx.x];
    if (gid == 0) C[n] = ne;
}

// ---- pass 2: CSR fill, NO atomics: pos = C[dst] + off[e]
__global__ void fill_kernel(const int* __restrict__ src, const int* __restrict__ dst,
                            const float* __restrict__ ew, const int* __restrict__ C,
                            const int* __restrict__ off, float2* __restrict__ edata, int ne) {
    int e = blockIdx.x * blockDim.x + threadIdx.x;
    if (e >= ne) return;
    int d = dst[e];
    int pos = C[d] + off[e];
    float2 v;
    v.x = __int_as_float(src[e]);
    v.y = sigmoidf_(ew[e]);
    edata[pos] = v;
}

// ---- deg from CSR rows (sequential, no atomics): dinv = rsqrt(1 + sum_row sig)
__global__ void degcsr_kernel(const int* __restrict__ C, const float2* __restrict__ edata,
                              float* __restrict__ dinv, int n) {
    int i = blockIdx.x * blockDim.x + threadIdx.x;
    if (i >= n) return;
    int beg = C[i], end = C[i + 1];
    float s = 0.0f;
    for (int k = beg; k < end; ++k) s += edata[k].y;
    dinv[i] = rsqrtf(s + 1.0f);
}

// ---- layer-1 pre-transform: g0 = dinv (.) (x @ W1)   (7 -> 8)
__global__ void xw1_kernel(const float* __restrict__ x, const float* __restrict__ W,
                           const float* __restrict__ dinv, float* __restrict__ g, int n) {
    __shared__ float Ws[56];
    if (threadIdx.x < 56) Ws[threadIdx.x] = W[threadIdx.x];
    __syncthreads();
    int i = blockIdx.x * blockDim.x + threadIdx.x;
    if (i >= n) return;
    float xi[7];
#pragma unroll
    for (int k = 0; k < 7; ++k) xi[k] = x[(size_t)i * 7 + k];
    float dv = dinv[i];
#pragma unroll
    for (int o = 0; o < 8; ++o) {
        float acc = 0.0f;
#pragma unroll
        for (int k = 0; k < 7; ++k) acc = fmaf(xi[k], Ws[k * 8 + o], acc);
        g[(size_t)i * 8 + o] = acc * dv;
    }
}

// ---- gather-reduce over CSR row: t = g[i] + sum sig*g[src]; F/4 lanes per node
// L1 mode: out = dinv * relu(dinv * t + bias)   (produces g1 directly)
// mid mode: out = dinv * t                      (raw input for next dense)
template <int F, bool L1>
__global__ void gather_kernel(const float* __restrict__ g, const float* __restrict__ dinv,
                              const int* __restrict__ C, const float2* __restrict__ edata,
                              const float* __restrict__ bias, float* __restrict__ out, int n) {
    constexpr int L = F / 4;
    long long t = (long long)blockIdx.x * blockDim.x + threadIdx.x;
    int i = (int)(t / L);
    int c = (int)(t % L);
    if (i >= n) return;
    int beg = C[i], end = C[i + 1];
    float4 acc = *reinterpret_cast<const float4*>(g + (size_t)i * F + c * 4);
    for (int k = beg; k < end; ++k) {
        float2 ed = edata[k];
        int s = __float_as_int(ed.x);
        float w = ed.y;
        float4 v = *reinterpret_cast<const float4*>(g + (size_t)s * F + c * 4);
        acc.x = fmaf(v.x, w, acc.x);
        acc.y = fmaf(v.y, w, acc.y);
        acc.z = fmaf(v.z, w, acc.z);
        acc.w = fmaf(v.w, w, acc.w);
    }
    float dv = dinv[i];
    if (L1) {
        acc.x = dv * fmaxf(dv * acc.x + bias[c * 4 + 0], 0.0f);
        acc.y = dv * fmaxf(dv * acc.y + bias[c * 4 + 1], 0.0f);
        acc.z = dv * fmaxf(dv * acc.z + bias[c * 4 + 2], 0.0f);
        acc.w = dv * fmaxf(dv * acc.w + bias[c * 4 + 3], 0.0f);
    } else {
        acc.x *= dv; acc.y *= dv; acc.z *= dv; acc.w *= dv;
    }
    *reinterpret_cast<float4*>(out + (size_t)i * F + c * 4) = acc;
}

// ---- dense + relu + dinv: out = dinv (.) relu(raw @ W + b)  (produces g for next gather)
template <int IN, int OUT>
__global__ void dense_kernel(const float* __restrict__ raw, const float* __restrict__ W,
                             const float* __restrict__ b, const float* __restrict__ dinv,
                             float* __restrict__ out, int n) {
    __shared__ float Ws[IN * OUT];
    __shared__ float bs[OUT];
    for (int k = threadIdx.x; k < IN * OUT; k += blockDim.x) Ws[k] = W[k];
    if (threadIdx.x < OUT) bs[threadIdx.x] = b[threadIdx.x];
    __syncthreads();
    int i = blockIdx.x * blockDim.x + threadIdx.x;
    if (i >= n) return;
    float xi[IN];
#pragma unroll
    for (int c = 0; c < IN / 4; ++c) {
        float4 v = *reinterpret_cast<const float4*>(raw + (size_t)i * IN + c * 4);
        xi[c * 4 + 0] = v.x; xi[c * 4 + 1] = v.y; xi[c * 4 + 2] = v.z; xi[c * 4 + 3] = v.w;
    }
    float dv = dinv[i];
#pragma unroll
    for (int o = 0; o < OUT; ++o) {
        float acc = bs[o];
#pragma unroll
        for (int k = 0; k < IN; ++k) acc = fmaf(xi[k], Ws[k * OUT + o], acc);
        out[(size_t)i * OUT + o] = dv * fmaxf(acc, 0.0f);
    }
}

// ---- fuse head weights: wf[64*3] = Wl1[64,4] @ Wl2[4,3]; bf[3] = bl1 @ Wl2 + bl2
__global__ void fuse_kernel(const float* __restrict__ Wl1, const float* __restrict__ bl1,
                            const float* __restrict__ Wl2, const float* __restrict__ bl2,
                            float* __restrict__ wf, float* __restrict__ bf) {
    int t = threadIdx.x;
    if (t < 64 * 3) {
        int f = t / 3, j = t % 3;
        float acc = 0.0f;
#pragma unroll
        for (int k = 0; k < 4; ++k) acc = fmaf(Wl1[f * 4 + k], Wl2[k * 3 + j], acc);
        wf[t] = acc;
    }
    if (t < 3) {
        float acc = bl2[t];
#pragma unroll
        for (int k = 0; k < 4; ++k) acc = fmaf(bl1[k], Wl2[k * 3 + t], acc);
        bf[t] = acc;
    }
}

// ---- layer-3 dense fused with head projection (h3 never materialized):
// h = relu(raw16 @ W3 + b3); p = h@wf[0:32] + bf; q = h@wf[32:64]
__global__ void dense3_kernel(const float* __restrict__ raw, const float* __restrict__ W,
                              const float* __restrict__ b, const float* __restrict__ wf,
                              const float* __restrict__ bf, float* __restrict__ pq, int n) {
    __shared__ float Ws[512];
    __shared__ float bs[32];
    __shared__ float wfs[192];
    __shared__ float bfs[3];
    for (int k = threadIdx.x; k < 512; k += blockDim.x) Ws[k] = W[k];
    if (threadIdx.x < 32) bs[threadIdx.x] = b[threadIdx.x];
    for (int k = threadIdx.x; k < 192; k += blockDim.x) wfs[k] = wf[k];
    if (threadIdx.x < 3) bfs[threadIdx.x] = bf[threadIdx.x];
    __syncthreads();
    int i = blockIdx.x * blockDim.x + threadIdx.x;
    if (i >= n) return;
    float xi[16];
#pragma unroll
    for (int c = 0; c < 4; ++c) {
        float4 v = *reinterpret_cast<const float4*>(raw + (size_t)i * 16 + c * 4);
        xi[c * 4 + 0] = v.x; xi[c * 4 + 1] = v.y; xi[c * 4 + 2] = v.z; xi[c * 4 + 3] = v.w;
    }
    float p0 = bfs[0], p1 = bfs[1], p2 = bfs[2];
    float q0 = 0.0f, q1 = 0.0f, q2 = 0.0f;
#pragma unroll
    for (int o = 0; o < 32; ++o) {
        float h = bs[o];
#pragma unroll
        for (int k = 0; k < 16; ++k) h = fmaf(xi[k], Ws[k * 32 + o], h);
        h = fmaxf(h, 0.0f);
        p0 = fmaf(h, wfs[o * 3 + 0], p0);
        p1 = fmaf(h, wfs[o * 3 + 1], p1);
        p2 = fmaf(h, wfs[o * 3 + 2], p2);
        q0 = fmaf(h, wfs[(32 + o) * 3 + 0], q0);
        q1 = fmaf(h, wfs[(32 + o) * 3 + 1], q1);
        q2 = fmaf(h, wfs[(32 + o) * 3 + 2], q2);
    }
    float4 P = {p0, p1, p2, 0.0f};
    float4 Q = {q0, q1, q2, 0.0f};
    *reinterpret_cast<float4*>(pq + (size_t)i * 8 + 0) = P;
    *reinterpret_cast<float4*>(pq + (size_t)i * 8 + 4) = Q;
}

// ---- head: out[e] = p[a] + q[b]
__global__ void head_kernel(const int* __restrict__ w2b, const float4* __restrict__ pq,
                            float* __restrict__ out, int nw) {
    int e = blockIdx.x * blockDim.x + threadIdx.x;
    if (e >= nw) return;
    int a = w2b[e];
    int b = w2b[(size_t)nw + e];
    float4 P = pq[(size_t)a * 2 + 0];
    float4 Q = pq[(size_t)b * 2 + 1];
    out[(size_t)e * 3 + 0] = P.x + Q.x;
    out[(size_t)e * 3 + 1] = P.y + Q.y;
    out[(size_t)e * 3 + 2] = P.z + Q.z;
}

extern "C" void kernel_launch(void* const* d_in, const int* in_sizes, int n_in,
                              void* d_out, int out_size, void* d_ws, size_t ws_size,
                              hipStream_t stream) {
    const float* x   = (const float*)d_in[0];
    const int* eidx  = (const int*)d_in[1];
    const int* w2b   = (const int*)d_in[2];
    const float* ew  = (const float*)d_in[3];
    const float* W1  = (const float*)d_in[4];
    const float* b1  = (const float*)d_in[5];
    const float* W2  = (const float*)d_in[6];
    const float* b2  = (const float*)d_in[7];
    const float* W3  = (const float*)d_in[8];
    const float* b3  = (const float*)d_in[9];
    const float* Wl1 = (const float*)d_in[10];
    const float* bl1 = (const float*)d_in[11];
    const float* Wl2 = (const float*)d_in[12];
    const float* bl2 = (const float*)d_in[13];
    float* out = (float*)d_out;

    const int n  = in_sizes[0] / 7;   // 200000
    const int ne = in_sizes[1] / 2;   // 4000000
    const int nw = in_sizes[2] / 2;   // 2000000
    const int* src = eidx;
    const int* dst = eidx + ne;

    // ---- workspace layout (floats) ----
    float* ws    = (float*)d_ws;
    float* dinv  = ws;                              // n
    int*   cnt   = (int*)(ws + n);                  // n
    int*   C     = (int*)(ws + 2 * (size_t)n);      // n+1 (+pad 16)
    int*   bsum  = (int*)(ws + 3 * (size_t)n + 16); // 1024
    float* wf    = ws + 3 * (size_t)n + 16 + 1024;  // 192
    float* bf    = wf + 192;                        // 16
    float* edata = bf + 16;                         // 2*ne (float2 per edge)
    float* A     = edata + 2 * (size_t)ne;          // 16n
    float* B_    = A + (size_t)n * 16;              // 16n
    float* pq    = B_ + (size_t)n * 16;             // 8n
    int*   off   = (int*)A;                         // ne ints, aliases A/B_ (dead until xw1)
    // total = 43n + 2ne + ~1.3K floats ~= 66.5 MB

    const int Bl = 256;
    auto blks = [&](long long t) { return (int)((t + Bl - 1) / Bl); };
    const int nb = blks(n);  // 782

    // 1. histogram + per-edge offsets (only atomic pass)
    (void)hipMemsetAsync(cnt, 0, (size_t)n * sizeof(int), stream);
    count_kernel<<<blks(ne), Bl, 0, stream>>>(dst, cnt, off, ne);

    // 2. exclusive scan cnt -> C (row starts), C[n] = ne
    scan1_kernel<<<nb, Bl, 0, stream>>>(cnt, C, bsum, n);
    scan2_kernel<<<1, 1024, 0, stream>>>(bsum, nb);
    scan3_kernel<<<nb, Bl, 0, stream>>>(C, bsum, n, ne);

    // 3. CSR fill (no atomics)
    fill_kernel<<<blks(ne), Bl, 0, stream>>>(src, dst, ew, C, off, (float2*)edata, ne);

    // 4. dinv from CSR (no atomics)
    degcsr_kernel<<<nb, Bl, 0, stream>>>(C, (const float2*)edata, dinv, n);

    // 5. layer 1: g0 = dinv(.)(x@W1) -> A ; g1 = dinv*relu(dinv*gather + b1) -> B
    xw1_kernel<<<nb, Bl, 0, stream>>>(x, W1, dinv, A, n);
    gather_kernel<8, true><<<blks((long long)n * 2), Bl, 0, stream>>>(
        A, dinv, C, (const float2*)edata, b1, B_, n);

    // 6. layer 2: raw2 = dinv*gather(g1) -> A ; g2 = dinv(.)relu(raw2@W2+b2) -> B
    gather_kernel<8, false><<<blks((long long)n * 2), Bl, 0, stream>>>(
        B_, dinv, C, (const float2*)edata, nullptr, A, n);
    dense_kernel<8, 16><<<nb, Bl, 0, stream>>>(A, W2, b2, dinv, B_, n);

    // 7. layer 3 + head projection: raw3 = dinv*gather(g2) -> A ; pq = dense3(raw3)
    gather_kernel<16, false><<<blks((long long)n * 4), Bl, 0, stream>>>(
        B_, dinv, C, (const float2*)edata, nullptr, A, n);
    fuse_kernel<<<1, 192, 0, stream>>>(Wl1, bl1, Wl2, bl2, wf, bf);
    dense3_kernel<<<nb, Bl, 0, stream>>>(A, W3, b3, wf, bf, pq, n);

    // 8. head: out[e] = p[a] + q[b]
    head_kernel<<<blks(nw), Bl, 0, stream>>>(w2b, (const float4*)pq, out, nw);
}